// Round 9
// baseline (157.264 us; speedup 1.0000x reference)
//
#include <hip/hip_runtime.h>
#include <hip/hip_bf16.h>
#include <cstddef>

// out[b,d,p] = sum_{t=0..62} filt[t] * act[b, (d+31-t) & 511, p]
// Banded circulant via mfma_f32_32x32x16_bf16.  Round 9: HALF-CHANNEL
// blocks for 2x residency. Each block computes 256 d-rows of one 32-hw
// tile, staging the 320-row c-band it reads (256 own + 64 halo) as bf16
// in LDS [hw][c_local] (20 KB -> 8 blocks/CU = 32 waves/CU, HW max).
// Stage/swizzle/MFMA/store structure identical to round 3 otherwise.

#define NC    512
#define HW    3136          // 56*56
#define NT    32            // hw positions per tile
#define NTILE (HW / NT)     // 98
#define NB    32
#define TPB   256
#define CROWS 320           // staged c rows per block (256 + 64 halo)
#define LROW  (CROWS * 2)   // LDS row stride bytes = 640 (5 x 128B blocks)

typedef __attribute__((ext_vector_type(8)))  short bf16x8;
typedef __attribute__((ext_vector_type(4)))  float f32x4;
typedef __attribute__((ext_vector_type(16))) float f32x16;

__device__ __forceinline__ short f2bf(float f) {
    union { __hip_bfloat16 h; short s; } u;
    u.h = __float2bfloat16(f);
    return u.s;
}

__device__ __forceinline__ int swzf(int hw) {
    return (((hw & 7) ^ (hw >> 3)) << 4);   // flips bits 4-6: stays in 128B block
}

__global__ __launch_bounds__(TPB, 8)
void toeplitz_half_kernel(const float* __restrict__ act,
                          const float* __restrict__ filt,
                          float* __restrict__ out) {
    // bf16 band [hw][c_local]: byte = hw*640 + ((cl*2) ^ swzf(hw)).  20 KB.
    __shared__ __align__(16) unsigned short xs[NT * CROWS];

    const int tid  = threadIdx.x;
    const int wv   = tid >> 6;          // wave 0..3
    const int ln   = tid & 63;
    const int bx   = blockIdx.x;
    const int ch   = bx & 1;            // d-half: rows [ch*256, ch*256+256)
    const int rest = bx >> 1;
    const int b    = rest / NTILE;
    const int tile = rest - b * NTILE;
    const int hw0  = tile * NT;
    const int D0   = ch * 256;

    // ---- A fragments: A_delta[r,k] = filt[delta + 31 + r - k] (0 outside)
    // lane: r = ln&31, k = (ln>>5)*8 + i.  delta(m) = 32 - 16*m, m=0..5
    const int r_a = ln & 31;
    const int k0  = (ln >> 5) * 8;
    bf16x8 af[6];
    #pragma unroll
    for (int m = 0; m < 6; ++m) {
        const int delta = 32 - 16 * m;
        #pragma unroll
        for (int i = 0; i < 8; ++i) {
            const int t = delta + 31 + r_a - (k0 + i);
            af[m][i] = (t >= 0 && t < 63) ? f2bf(filt[t]) : (short)0;
        }
    }

    // ---- stage band: global rows gr = (D0 - 32 + cl) & 511, cl in [0,320).
    // wave wv covers cl in [wv*80, wv*80+80): 5 iters x 16 rows (paired).
    {
        const float* gb = act + (size_t)b * NC * HW + hw0;
        const int g = ln >> 3;      // 0..7 row-pair group
        const int q = ln & 7;       // hw quad
        const int GR0 = D0 + 480;   // == D0 - 32 (mod 512), even
        #pragma unroll
        for (int j = 0; j < 5; ++j) {
            const int cl0 = wv * 80 + j * 16 + 2 * g;            // even
            const int r0  = (GR0 + cl0) & (NC - 1);              // even, pair safe
            const f32x4 a0 = *reinterpret_cast<const f32x4*>(gb + (size_t)r0 * HW + 4 * q);
            const f32x4 a1 = *reinterpret_cast<const f32x4*>(gb + (size_t)(r0 + 1) * HW + 4 * q);
            #pragma unroll
            for (int t4 = 0; t4 < 4; ++t4) {
                const int hw = 4 * q + t4;
                const unsigned int pk = (unsigned int)(unsigned short)f2bf(a0[t4])
                                      | ((unsigned int)(unsigned short)f2bf(a1[t4]) << 16);
                const int byte = hw * LROW + ((cl0 * 2) ^ swzf(hw));
                *reinterpret_cast<unsigned int*>(reinterpret_cast<char*>(xs) + byte) = pk;
            }
        }
    }
    __syncthreads();

    // ---- compute: wave wv owns d-rows [D0 + wv*64, +64): 2 d-tiles of 32.
    // Fragment window w[0..7] at local c = wv*64 + 16u; tile j uses w[2j..2j+5].
    const int hwl     = ln & 31;
    const int rowbyte = hwl * LROW;
    const int swzv    = swzf(hwl);
    const int kb      = (ln >> 5) * 16;   // byte offset of k-half

    bf16x8 w[8];
    {
        const int clb = wv * 64;          // local c of first fragment
        #pragma unroll
        for (int u = 0; u < 8; ++u) {
            const int byte = rowbyte + ((((clb + 16 * u) * 2) + kb) ^ swzv);
            w[u] = *reinterpret_cast<const bf16x8*>(
                reinterpret_cast<const char*>(xs) + byte);
        }
    }

    float* ob = out + (size_t)b * NC * HW + hw0 + hwl;
    const int rhalf = (ln >> 5) * 4;
    const int dw    = D0 + wv * 64;

    #pragma unroll
    for (int j = 0; j < 2; ++j) {
        const int d0 = dw + j * 32;
        f32x16 acc;
        #pragma unroll
        for (int r = 0; r < 16; ++r) acc[r] = 0.0f;
        #pragma unroll
        for (int m = 0; m < 6; ++m)     // c0 = d0-32+16m, delta = 32-16m
            acc = __builtin_amdgcn_mfma_f32_32x32x16_bf16(af[m], w[2 * j + m], acc, 0, 0, 0);
        #pragma unroll
        for (int r = 0; r < 16; ++r) {
            const int row = d0 + (r & 3) + 8 * (r >> 2) + rhalf;
            __builtin_nontemporal_store(acc[r], ob + (size_t)row * HW);
        }
    }
}

extern "C" void kernel_launch(void* const* d_in, const int* in_sizes, int n_in,
                              void* d_out, int out_size, void* d_ws, size_t ws_size,
                              hipStream_t stream) {
    const float* act  = (const float*)d_in[0];   // (32, 512, 56, 56) f32
    const float* filt = (const float*)d_in[1];   // (1, 1, 63) f32
    float* out = (float*)d_out;                  // (32, 512, 56, 56) f32
    dim3 grid(NB * NTILE * 2);    // 6272
    dim3 block(TPB);
    hipLaunchKernelGGL(toeplitz_half_kernel, grid, block, 0, stream,
                       act, filt, out);
}

// Round 10
// 76.331 us; speedup vs baseline: 2.0603x; 2.0603x over previous
//
#include <hip/hip_runtime.h>
#include <hip/hip_bf16.h>
#include <cstddef>

// out[b,d,p] = sum_{t=0..62} filt[t] * act[b, (d+31-t) & 511, p]
// Banded circulant via mfma_f32_32x32x16_bf16.  Round 10: half-channel
// blocks (2x residency) as round 9, but __launch_bounds__(256,4) so the
// allocator is NOT capped at 64 VGPRs (R9 spilled ~31 dwords/thread under
// the (256,8) cap: WRITE 401 MB, FETCH 226 MB, VGPR=32). Occupancy stays
// LDS-limited at ~6 blocks/CU (20 KB/block, ~120 KB usable pool).

#define NC    512
#define HW    3136          // 56*56
#define NT    32            // hw positions per tile
#define NTILE (HW / NT)     // 98
#define NB    32
#define TPB   256
#define CROWS 320           // staged c rows per block (256 + 64 halo)
#define LROW  (CROWS * 2)   // LDS row stride bytes = 640 (5 x 128B blocks)

typedef __attribute__((ext_vector_type(8)))  short bf16x8;
typedef __attribute__((ext_vector_type(4)))  float f32x4;
typedef __attribute__((ext_vector_type(16))) float f32x16;

__device__ __forceinline__ short f2bf(float f) {
    union { __hip_bfloat16 h; short s; } u;
    u.h = __float2bfloat16(f);
    return u.s;
}

__device__ __forceinline__ int swzf(int hw) {
    return (((hw & 7) ^ (hw >> 3)) << 4);   // flips bits 4-6: stays in 128B block
}

__global__ __launch_bounds__(TPB, 4)
void toeplitz_half_kernel(const float* __restrict__ act,
                          const float* __restrict__ filt,
                          float* __restrict__ out) {
    // bf16 band [hw][c_local]: byte = hw*640 + ((cl*2) ^ swzf(hw)).  20 KB.
    __shared__ __align__(16) unsigned short xs[NT * CROWS];

    const int tid  = threadIdx.x;
    const int wv   = tid >> 6;          // wave 0..3
    const int ln   = tid & 63;
    const int bx   = blockIdx.x;
    const int ch   = bx & 1;            // d-half: rows [ch*256, ch*256+256)
    const int rest = bx >> 1;
    const int b    = rest / NTILE;
    const int tile = rest - b * NTILE;
    const int hw0  = tile * NT;
    const int D0   = ch * 256;

    // ---- A fragments: A_delta[r,k] = filt[delta + 31 + r - k] (0 outside)
    // lane: r = ln&31, k = (ln>>5)*8 + i.  delta(m) = 32 - 16*m, m=0..5
    const int r_a = ln & 31;
    const int k0  = (ln >> 5) * 8;
    bf16x8 af[6];
    #pragma unroll
    for (int m = 0; m < 6; ++m) {
        const int delta = 32 - 16 * m;
        #pragma unroll
        for (int i = 0; i < 8; ++i) {
            const int t = delta + 31 + r_a - (k0 + i);
            af[m][i] = (t >= 0 && t < 63) ? f2bf(filt[t]) : (short)0;
        }
    }

    // ---- stage band: global rows gr = (D0 - 32 + cl) & 511, cl in [0,320).
    // wave wv covers cl in [wv*80, wv*80+80): 5 iters x 16 rows (paired).
    {
        const float* gb = act + (size_t)b * NC * HW + hw0;
        const int g = ln >> 3;      // 0..7 row-pair group
        const int q = ln & 7;       // hw quad
        const int GR0 = D0 + 480;   // == D0 - 32 (mod 512), even
        #pragma unroll
        for (int j = 0; j < 5; ++j) {
            const int cl0 = wv * 80 + j * 16 + 2 * g;            // even
            const int r0  = (GR0 + cl0) & (NC - 1);              // even, pair safe
            const f32x4 a0 = *reinterpret_cast<const f32x4*>(gb + (size_t)r0 * HW + 4 * q);
            const f32x4 a1 = *reinterpret_cast<const f32x4*>(gb + (size_t)(r0 + 1) * HW + 4 * q);
            #pragma unroll
            for (int t4 = 0; t4 < 4; ++t4) {
                const int hw = 4 * q + t4;
                const unsigned int pk = (unsigned int)(unsigned short)f2bf(a0[t4])
                                      | ((unsigned int)(unsigned short)f2bf(a1[t4]) << 16);
                const int byte = hw * LROW + ((cl0 * 2) ^ swzf(hw));
                *reinterpret_cast<unsigned int*>(reinterpret_cast<char*>(xs) + byte) = pk;
            }
        }
    }
    __syncthreads();

    // ---- compute: wave wv owns d-rows [D0 + wv*64, +64): 2 d-tiles of 32.
    // Fragment window w[0..7] at local c = wv*64 + 16u; tile j uses w[2j..2j+5].
    const int hwl     = ln & 31;
    const int rowbyte = hwl * LROW;
    const int swzv    = swzf(hwl);
    const int kb      = (ln >> 5) * 16;   // byte offset of k-half

    bf16x8 w[8];
    {
        const int clb = wv * 64;          // local c of first fragment
        #pragma unroll
        for (int u = 0; u < 8; ++u) {
            const int byte = rowbyte + ((((clb + 16 * u) * 2) + kb) ^ swzv);
            w[u] = *reinterpret_cast<const bf16x8*>(
                reinterpret_cast<const char*>(xs) + byte);
        }
    }

    float* ob = out + (size_t)b * NC * HW + hw0 + hwl;
    const int rhalf = (ln >> 5) * 4;
    const int dw    = D0 + wv * 64;

    #pragma unroll
    for (int j = 0; j < 2; ++j) {
        const int d0 = dw + j * 32;
        f32x16 acc;
        #pragma unroll
        for (int r = 0; r < 16; ++r) acc[r] = 0.0f;
        #pragma unroll
        for (int m = 0; m < 6; ++m)     // c0 = d0-32+16m, delta = 32-16m
            acc = __builtin_amdgcn_mfma_f32_32x32x16_bf16(af[m], w[2 * j + m], acc, 0, 0, 0);
        #pragma unroll
        for (int r = 0; r < 16; ++r) {
            const int row = d0 + (r & 3) + 8 * (r >> 2) + rhalf;
            __builtin_nontemporal_store(acc[r], ob + (size_t)row * HW);
        }
    }
}

extern "C" void kernel_launch(void* const* d_in, const int* in_sizes, int n_in,
                              void* d_out, int out_size, void* d_ws, size_t ws_size,
                              hipStream_t stream) {
    const float* act  = (const float*)d_in[0];   // (32, 512, 56, 56) f32
    const float* filt = (const float*)d_in[1];   // (1, 1, 63) f32
    float* out = (float*)d_out;                  // (32, 512, 56, 56) f32
    dim3 grid(NB * NTILE * 2);    // 6272
    dim3 block(TPB);
    hipLaunchKernelGGL(toeplitz_half_kernel, grid, block, 0, stream,
                       act, filt, out);
}